// Round 2
// baseline (543.007 us; speedup 1.0000x reference)
//
#include <hip/hip_runtime.h>

typedef __attribute__((ext_vector_type(8))) short short8;
typedef __attribute__((ext_vector_type(4))) float f32x4;
typedef __attribute__((ext_vector_type(4))) unsigned int u32x4;

#define MAXNORM 0.996f        // (1 - 4e-3)/sqrt(c), c=1
#define MINNORM 1e-15f
#define ATEPS   (1.0f - 1e-7f)

__device__ __forceinline__ float frcp(float x) { return __builtin_amdgcn_rcpf(x); }
// artanh on [0, 1-1e-7] with the reference clamp folded in
__device__ __forceinline__ float artanh_c(float z) {
    z = fminf(z, ATEPS);
    return 0.5f * __logf((1.0f + z) * frcp(1.0f - z));
}
// tanh for a >= 0
__device__ __forceinline__ float tanh_pos(float a) {
    float e = __expf(-2.0f * a);
    return (1.0f - e) * frcp(1.0f + e);
}
// fp32 -> bf16 bits, round-to-nearest-even (prologue only; hot path uses cvt_pk)
__device__ __forceinline__ unsigned short f2bf(float f) {
    union { float f; unsigned u; } v; v.f = f;
    unsigned r = v.u + 0x7FFFu + ((v.u >> 16) & 1u);
    return (unsigned short)(r >> 16);
}
// packed fp32x2 -> bf16x2, RNE (same rounding as f2bf), 1 instruction
__device__ __forceinline__ unsigned cvt_pk_bf16(float lo, float hi) {
    unsigned r;
    asm("v_cvt_pk_bf16_f32 %0, %1, %2" : "=v"(r) : "v"(lo), "v"(hi));
    return r;
}

// ---- prologue: pack W (fp32 [128,128]) into bf16 MFMA B-fragments ----
// Wp[(nt*4+ks)*64 + lane] = short8 { f2bf(W[nt*16+c][ks*32+q*8 + j]) }
__global__ __launch_bounds__(256) void wpack_kernel(
    const float* __restrict__ Wf, short8* __restrict__ Wp)
{
    const int tid = blockIdx.x * 256 + threadIdx.x;   // 0..2047
    const int l = tid & 63;
    const int f = tid >> 6;        // fragment id 0..31
    const int nt = f >> 2, ks = f & 3;
    const int c = l & 15, q = l >> 4;
    const float* src = Wf + (nt * 16 + c) * 128 + ks * 32 + q * 8;
    short8 s;
    #pragma unroll
    for (int j = 0; j < 4; ++j) {
        s[j]     = (short)f2bf(src[j]);
        s[4 + j] = (short)f2bf(src[4 + j]);
    }
    Wp[tid] = s;
}

__global__ __launch_bounds__(256, 4) void blinear_kernel(
    const float* __restrict__ Xf,   // [N,128] fp32
    const short8* __restrict__ Wp,  // [32][64] packed bf16 B-fragments (32 KB)
    const float* __restrict__ Bf,   // [128] fp32
    float* __restrict__ Out)        // [N,128] fp32
{
    const int lane = threadIdx.x & 63;
    const int wave = threadIdx.x >> 6;
    const int c = lane & 15;   // col within 16x16 tile / A-row selector
    const int q = lane >> 4;   // quad (k-group selector; row-group in C layout)
    const long rowbase = (long)blockIdx.x * 128 + wave * 32;   // 32 rows per wave

    // ---- bias prologue (per-wave, redundant, no LDS) ----
    float b0 = Bf[lane];
    float b1 = Bf[64 + lane];
    float bn2 = b0 * b0 + b1 * b1;
    #pragma unroll
    for (int m = 1; m <= 32; m <<= 1) bn2 += __shfl_xor(bn2, m);
    float bn = fmaxf(sqrtf(bn2), MINNORM);
    float tb = tanh_pos(bn);
    float fb = fminf(tb, MAXNORM) * frcp(bn);
    float hb2 = fb * fb * bn2;                 // sum(hb^2); wave-uniform
    float hbv[8];                              // hb at cols nt*16 + c
    #pragma unroll
    for (int nt = 0; nt < 8; ++nt) hbv[nt] = fb * Bf[nt * 16 + c];

    // ---- A fragments: X read once (fp32), packed to bf16 via cvt_pk; Sum(x^2) fp32 ----
    short8 afr[2][4];
    float xq[2] = {0.0f, 0.0f};
    #pragma unroll
    for (int t = 0; t < 2; ++t) {
        const float* xrow = Xf + (rowbase + t * 16 + c) * 128;
        #pragma unroll
        for (int ks = 0; ks < 4; ++ks) {
            f32x4 a0 = *(const f32x4*)(xrow + ks * 32 + q * 8);
            f32x4 a1 = *(const f32x4*)(xrow + ks * 32 + q * 8 + 4);
            #pragma unroll
            for (int j = 0; j < 4; ++j)
                xq[t] = fmaf(a0[j], a0[j], fmaf(a1[j], a1[j], xq[t]));
            union { u32x4 u; short8 s; } cv;
            cv.u[0] = cvt_pk_bf16(a0[0], a0[1]);
            cv.u[1] = cvt_pk_bf16(a0[2], a0[3]);
            cv.u[2] = cvt_pk_bf16(a1[0], a1[1]);
            cv.u[3] = cvt_pk_bf16(a1[2], a1[3]);
            afr[t][ks] = cv.s;
        }
    }
    // reduce Sum(x^2) across the 4 quads (each quad holds a disjoint k-range)
    #pragma unroll
    for (int t = 0; t < 2; ++t) { xq[t] += __shfl_xor(xq[t], 16); xq[t] += __shfl_xor(xq[t], 32); }
    // redistribute to C-layout row owner (row = t*16 + q*4 + r)
    float xn2v[2][4];
    #pragma unroll
    for (int t = 0; t < 2; ++t)
        #pragma unroll
        for (int r = 0; r < 4; ++r) xn2v[t][r] = __shfl(xq[t], q * 4 + r);

    // ---- GEMM: mx = X @ W^T, 16x16x32 bf16 MFMA; B-fragments pre-packed ----
    f32x4 acc[2][8];
    {
        f32x4 z = {0.0f, 0.0f, 0.0f, 0.0f};
        #pragma unroll
        for (int t = 0; t < 2; ++t)
            #pragma unroll
            for (int nt = 0; nt < 8; ++nt) acc[t][nt] = z;
    }
    #pragma unroll
    for (int nt = 0; nt < 8; ++nt) {
        #pragma unroll
        for (int ks = 0; ks < 4; ++ks) {
            short8 bfr = Wp[(nt * 4 + ks) * 64 + lane];
            acc[0][nt] = __builtin_amdgcn_mfma_f32_16x16x32_bf16(afr[0][ks], bfr, acc[0][nt], 0, 0, 0);
            acc[1][nt] = __builtin_amdgcn_mfma_f32_16x16x32_bf16(afr[1][ks], bfr, acc[1][nt], 0, 0, 0);
        }
    }

    // ---- round-1 reductions over cols: mn2 = sum(mx^2); mhb only if hb != 0 ----
    // C layout: col = lane&15 (+16*nt), row = t*16 + q*4 + reg
    float mn2[2][4] = {}, mhb[2][4] = {};
    #pragma unroll
    for (int t = 0; t < 2; ++t)
        #pragma unroll
        for (int nt = 0; nt < 8; ++nt)
            #pragma unroll
            for (int r = 0; r < 4; ++r) {
                float v = acc[t][nt][r];
                mn2[t][r] = fmaf(v, v, mn2[t][r]);
            }
    #pragma unroll
    for (int m = 1; m <= 8; m <<= 1)
        #pragma unroll
        for (int t = 0; t < 2; ++t)
            #pragma unroll
            for (int r = 0; r < 4; ++r) mn2[t][r] += __shfl_xor(mn2[t][r], m);
    if (hb2 != 0.0f) {   // wave-uniform (hb2 reduced over all 64 lanes)
        #pragma unroll
        for (int t = 0; t < 2; ++t)
            #pragma unroll
            for (int nt = 0; nt < 8; ++nt)
                #pragma unroll
                for (int r = 0; r < 4; ++r)
                    mhb[t][r] = fmaf(acc[t][nt][r], hbv[nt], mhb[t][r]);
        #pragma unroll
        for (int m = 1; m <= 8; m <<= 1)
            #pragma unroll
            for (int t = 0; t < 2; ++t)
                #pragma unroll
                for (int r = 0; r < 4; ++r) mhb[t][r] += __shfl_xor(mhb[t][r], m);
    }

    // ---- per-row scalar chain (each lane owns its quad's 4+4 rows) ----
    float A1[2][4], B1[2][4], SG[2][4];
    #pragma unroll
    for (int t = 0; t < 2; ++t)
        #pragma unroll
        for (int r = 0; r < 4; ++r) {
            float xn = fmaxf(sqrtf(xn2v[t][r]), MINNORM);
            float mn = fmaxf(sqrtf(mn2[t][r]), MINNORM);
            // mobius_matvec: res = tanh(mx_n/x_n * artanh(x_n)) * mx / mx_n, then proj
            float t1 = tanh_pos(mn * frcp(xn) * artanh_c(xn));
            float rn = fminf(t1, MAXNORM);          // ||res|| after proj
            float f1 = rn * frcp(mn);               // res = f1 * mx
            float x2 = rn * rn;
            // mobius_add(res, hb): res2 = (A*res + B*hb)/D
            float xy = f1 * mhb[t][r];
            float Aa = 1.0f + 2.0f * xy + hb2;
            float Bb = 1.0f - x2;
            float Dn = fmaxf(1.0f + 2.0f * xy + x2 * hb2, MINNORM);
            float rD = frcp(Dn);
            float a1 = Aa * f1 * rD;                // res2 = a1*mx + b1_*hb
            float b1_ = Bb * rD;
            float r2n2 = a1 * a1 * mn2[t][r] + 2.0f * a1 * b1_ * mhb[t][r] + b1_ * b1_ * hb2;
            float r2n = sqrtf(fmaxf(r2n2, 0.0f));
            float g = (r2n > MAXNORM) ? (MAXNORM * frcp(r2n)) : 1.0f;   // proj
            float n3 = fmaxf(fminf(r2n, MAXNORM), MINNORM);
            float s3 = artanh_c(n3) * frcp(n3);     // logmap0 scale (>0, commutes with relu)
            A1[t][r] = a1; B1[t][r] = b1_; SG[t][r] = s3 * g;
        }

    // ---- round-2 reduction: q2 = sum(max(a1*mx + b1_*hb, 0)^2) ----
    float q2[2][4] = {};
    if (hb2 != 0.0f) {
        #pragma unroll
        for (int t = 0; t < 2; ++t)
            #pragma unroll
            for (int nt = 0; nt < 8; ++nt)
                #pragma unroll
                for (int r = 0; r < 4; ++r) {
                    float v = fmaf(A1[t][r], acc[t][nt][r], B1[t][r] * hbv[nt]);
                    v = fmaxf(v, 0.0f);
                    acc[t][nt][r] = v;
                    q2[t][r] = fmaf(v, v, q2[t][r]);
                }
    } else {
        #pragma unroll
        for (int t = 0; t < 2; ++t)
            #pragma unroll
            for (int nt = 0; nt < 8; ++nt)
                #pragma unroll
                for (int r = 0; r < 4; ++r) {
                    float v = fmaxf(A1[t][r] * acc[t][nt][r], 0.0f);
                    acc[t][nt][r] = v;
                    q2[t][r] = fmaf(v, v, q2[t][r]);
                }
    }
    #pragma unroll
    for (int m = 1; m <= 8; m <<= 1)
        #pragma unroll
        for (int t = 0; t < 2; ++t)
            #pragma unroll
            for (int r = 0; r < 4; ++r) q2[t][r] += __shfl_xor(q2[t][r], m);

    // ---- final scale: logmap0-scale * proj-scale folded into expmap0 + proj ----
    float K[2][4];
    #pragma unroll
    for (int t = 0; t < 2; ++t)
        #pragma unroll
        for (int r = 0; r < 4; ++r) {
            float sg = SG[t][r];
            float tn_t = sg * sqrtf(q2[t][r]);      // ||relu(logmap0(res3))||
            float tn = fmaxf(tn_t, MINNORM);
            float t4 = tanh_pos(tn);
            K[t][r] = fminf(t4, MAXNORM) * frcp(tn) * sg;
        }

    // ---- store: out_j = K * relu_val, fp32, direct from C layout ----
    #pragma unroll
    for (int t = 0; t < 2; ++t)
        #pragma unroll
        for (int r = 0; r < 4; ++r) {
            long row = rowbase + t * 16 + q * 4 + r;
            float* orow = Out + row * 128;
            #pragma unroll
            for (int nt = 0; nt < 8; ++nt)
                orow[nt * 16 + c] = K[t][r] * acc[t][nt][r];
        }
}

extern "C" void kernel_launch(void* const* d_in, const int* in_sizes, int n_in,
                              void* d_out, int out_size, void* d_ws, size_t ws_size,
                              hipStream_t stream) {
    const float* X = (const float*)d_in[0];   // fp32 [N,128]
    const float* W = (const float*)d_in[1];   // fp32 [128,128]
    const float* B = (const float*)d_in[2];   // fp32 [128]
    float* Out = (float*)d_out;
    short8* Wp = (short8*)d_ws;               // 32 KB packed bf16 W
    const int N = in_sizes[0] / 128;          // 524288 rows
    wpack_kernel<<<8, 256, 0, stream>>>(W, Wp);
    blinear_kernel<<<N / 128, 256, 0, stream>>>(X, Wp, B, Out);  // 128 rows/block
}

// Round 3
// 449.904 us; speedup vs baseline: 1.2069x; 1.2069x over previous
//
#include <hip/hip_runtime.h>

typedef __attribute__((ext_vector_type(8))) short short8;
typedef __attribute__((ext_vector_type(4))) float f32x4;
typedef __attribute__((ext_vector_type(4))) unsigned int u32x4;

#define MAXNORM 0.996f        // (1 - 4e-3)/sqrt(c), c=1
#define MINNORM 1e-15f
#define ATEPS   (1.0f - 1e-7f)

__device__ __forceinline__ float frcp(float x) { return __builtin_amdgcn_rcpf(x); }
// artanh on [0, 1-1e-7] with the reference clamp folded in
__device__ __forceinline__ float artanh_c(float z) {
    z = fminf(z, ATEPS);
    return 0.5f * __logf((1.0f + z) * frcp(1.0f - z));
}
// tanh for a >= 0
__device__ __forceinline__ float tanh_pos(float a) {
    float e = __expf(-2.0f * a);
    return (1.0f - e) * frcp(1.0f + e);
}
// fp32 -> bf16 bits, round-to-nearest-even (prologue only; hot path uses cvt_pk)
__device__ __forceinline__ unsigned short f2bf(float f) {
    union { float f; unsigned u; } v; v.f = f;
    unsigned r = v.u + 0x7FFFu + ((v.u >> 16) & 1u);
    return (unsigned short)(r >> 16);
}
// packed fp32x2 -> bf16x2, RNE (same rounding as f2bf), 1 instruction
__device__ __forceinline__ unsigned cvt_pk_bf16(float lo, float hi) {
    unsigned r;
    asm("v_cvt_pk_bf16_f32 %0, %1, %2" : "=v"(r) : "v"(lo), "v"(hi));
    return r;
}

// ---- prologue: pack W (fp32 [128,128]) into bf16 MFMA B-fragments ----
// Wp[(nt*4+ks)*64 + lane] = short8 { f2bf(W[nt*16+c][ks*32+q*8 + j]) }
__global__ __launch_bounds__(256) void wpack_kernel(
    const float* __restrict__ Wf, short8* __restrict__ Wp)
{
    const int tid = blockIdx.x * 256 + threadIdx.x;   // 0..2047
    const int l = tid & 63;
    const int f = tid >> 6;        // fragment id 0..31
    const int nt = f >> 2, ks = f & 3;
    const int c = l & 15, q = l >> 4;
    const float* src = Wf + (nt * 16 + c) * 128 + ks * 32 + q * 8;
    short8 s;
    #pragma unroll
    for (int j = 0; j < 4; ++j) {
        s[j]     = (short)f2bf(src[j]);
        s[4 + j] = (short)f2bf(src[4 + j]);
    }
    Wp[tid] = s;
}

// NOTE: plain __launch_bounds__(256). Adding ",4" (waves-per-eu=4) makes the
// allocator cap ARCH VGPRs at 256/4=64 (AGPR half of the unified file not
// counted) -> acc[2][8] spills to scratch: +410 MB writes, +103 MB reads,
// dur 167->258 us measured. 32 rows/wave needs the full 128-VGPR slot.
__global__ __launch_bounds__(256) void blinear_kernel(
    const float* __restrict__ Xf,   // [N,128] fp32
    const short8* __restrict__ Wp,  // [32][64] packed bf16 B-fragments (32 KB)
    const float* __restrict__ Bf,   // [128] fp32
    float* __restrict__ Out)        // [N,128] fp32
{
    const int lane = threadIdx.x & 63;
    const int wave = threadIdx.x >> 6;
    const int c = lane & 15;   // col within 16x16 tile / A-row selector
    const int q = lane >> 4;   // quad (k-group selector; row-group in C layout)
    const long rowbase = (long)blockIdx.x * 128 + wave * 32;   // 32 rows per wave

    // ---- bias prologue (per-wave, redundant, no LDS) ----
    float b0 = Bf[lane];
    float b1 = Bf[64 + lane];
    float bn2 = b0 * b0 + b1 * b1;
    #pragma unroll
    for (int m = 1; m <= 32; m <<= 1) bn2 += __shfl_xor(bn2, m);
    float bn = fmaxf(sqrtf(bn2), MINNORM);
    float tb = tanh_pos(bn);
    float fb = fminf(tb, MAXNORM) * frcp(bn);
    float hb2 = fb * fb * bn2;                 // sum(hb^2); wave-uniform
    float hbv[8];                              // hb at cols nt*16 + c
    #pragma unroll
    for (int nt = 0; nt < 8; ++nt) hbv[nt] = fb * Bf[nt * 16 + c];

    // ---- A fragments: X read once (fp32), packed to bf16 via cvt_pk; Sum(x^2) fp32 ----
    short8 afr[2][4];
    float xq[2] = {0.0f, 0.0f};
    #pragma unroll
    for (int t = 0; t < 2; ++t) {
        const float* xrow = Xf + (rowbase + t * 16 + c) * 128;
        #pragma unroll
        for (int ks = 0; ks < 4; ++ks) {
            f32x4 a0 = *(const f32x4*)(xrow + ks * 32 + q * 8);
            f32x4 a1 = *(const f32x4*)(xrow + ks * 32 + q * 8 + 4);
            #pragma unroll
            for (int j = 0; j < 4; ++j)
                xq[t] = fmaf(a0[j], a0[j], fmaf(a1[j], a1[j], xq[t]));
            union { u32x4 u; short8 s; } cv;
            cv.u[0] = cvt_pk_bf16(a0[0], a0[1]);
            cv.u[1] = cvt_pk_bf16(a0[2], a0[3]);
            cv.u[2] = cvt_pk_bf16(a1[0], a1[1]);
            cv.u[3] = cvt_pk_bf16(a1[2], a1[3]);
            afr[t][ks] = cv.s;
        }
    }
    // reduce Sum(x^2) across the 4 quads (each quad holds a disjoint k-range)
    #pragma unroll
    for (int t = 0; t < 2; ++t) { xq[t] += __shfl_xor(xq[t], 16); xq[t] += __shfl_xor(xq[t], 32); }
    // redistribute to C-layout row owner (row = t*16 + q*4 + r)
    float xn2v[2][4];
    #pragma unroll
    for (int t = 0; t < 2; ++t)
        #pragma unroll
        for (int r = 0; r < 4; ++r) xn2v[t][r] = __shfl(xq[t], q * 4 + r);

    // ---- GEMM: mx = X @ W^T, 16x16x32 bf16 MFMA; B-fragments pre-packed ----
    f32x4 acc[2][8];
    {
        f32x4 z = {0.0f, 0.0f, 0.0f, 0.0f};
        #pragma unroll
        for (int t = 0; t < 2; ++t)
            #pragma unroll
            for (int nt = 0; nt < 8; ++nt) acc[t][nt] = z;
    }
    #pragma unroll
    for (int nt = 0; nt < 8; ++nt) {
        #pragma unroll
        for (int ks = 0; ks < 4; ++ks) {
            short8 bfr = Wp[(nt * 4 + ks) * 64 + lane];
            acc[0][nt] = __builtin_amdgcn_mfma_f32_16x16x32_bf16(afr[0][ks], bfr, acc[0][nt], 0, 0, 0);
            acc[1][nt] = __builtin_amdgcn_mfma_f32_16x16x32_bf16(afr[1][ks], bfr, acc[1][nt], 0, 0, 0);
        }
    }

    // ---- round-1 reductions over cols: mn2 = sum(mx^2); mhb only if hb != 0 ----
    // C layout: col = lane&15 (+16*nt), row = t*16 + q*4 + reg
    float mn2[2][4] = {}, mhb[2][4] = {};
    #pragma unroll
    for (int t = 0; t < 2; ++t)
        #pragma unroll
        for (int nt = 0; nt < 8; ++nt)
            #pragma unroll
            for (int r = 0; r < 4; ++r) {
                float v = acc[t][nt][r];
                mn2[t][r] = fmaf(v, v, mn2[t][r]);
            }
    #pragma unroll
    for (int m = 1; m <= 8; m <<= 1)
        #pragma unroll
        for (int t = 0; t < 2; ++t)
            #pragma unroll
            for (int r = 0; r < 4; ++r) mn2[t][r] += __shfl_xor(mn2[t][r], m);
    if (hb2 != 0.0f) {   // wave-uniform (hb2 reduced over all 64 lanes)
        #pragma unroll
        for (int t = 0; t < 2; ++t)
            #pragma unroll
            for (int nt = 0; nt < 8; ++nt)
                #pragma unroll
                for (int r = 0; r < 4; ++r)
                    mhb[t][r] = fmaf(acc[t][nt][r], hbv[nt], mhb[t][r]);
        #pragma unroll
        for (int m = 1; m <= 8; m <<= 1)
            #pragma unroll
            for (int t = 0; t < 2; ++t)
                #pragma unroll
                for (int r = 0; r < 4; ++r) mhb[t][r] += __shfl_xor(mhb[t][r], m);
    }

    // ---- per-row scalar chain (each lane owns its quad's 4+4 rows) ----
    float A1[2][4], B1[2][4], SG[2][4];
    #pragma unroll
    for (int t = 0; t < 2; ++t)
        #pragma unroll
        for (int r = 0; r < 4; ++r) {
            float xn = fmaxf(sqrtf(xn2v[t][r]), MINNORM);
            float mn = fmaxf(sqrtf(mn2[t][r]), MINNORM);
            // mobius_matvec: res = tanh(mx_n/x_n * artanh(x_n)) * mx / mx_n, then proj
            float t1 = tanh_pos(mn * frcp(xn) * artanh_c(xn));
            float rn = fminf(t1, MAXNORM);          // ||res|| after proj
            float f1 = rn * frcp(mn);               // res = f1 * mx
            float x2 = rn * rn;
            // mobius_add(res, hb): res2 = (A*res + B*hb)/D
            float xy = f1 * mhb[t][r];
            float Aa = 1.0f + 2.0f * xy + hb2;
            float Bb = 1.0f - x2;
            float Dn = fmaxf(1.0f + 2.0f * xy + x2 * hb2, MINNORM);
            float rD = frcp(Dn);
            float a1 = Aa * f1 * rD;                // res2 = a1*mx + b1_*hb
            float b1_ = Bb * rD;
            float r2n2 = a1 * a1 * mn2[t][r] + 2.0f * a1 * b1_ * mhb[t][r] + b1_ * b1_ * hb2;
            float r2n = sqrtf(fmaxf(r2n2, 0.0f));
            float g = (r2n > MAXNORM) ? (MAXNORM * frcp(r2n)) : 1.0f;   // proj
            float n3 = fmaxf(fminf(r2n, MAXNORM), MINNORM);
            float s3 = artanh_c(n3) * frcp(n3);     // logmap0 scale (>0, commutes with relu)
            A1[t][r] = a1; B1[t][r] = b1_; SG[t][r] = s3 * g;
        }

    // ---- round-2 reduction: q2 = sum(max(a1*mx + b1_*hb, 0)^2) ----
    float q2[2][4] = {};
    if (hb2 != 0.0f) {
        #pragma unroll
        for (int t = 0; t < 2; ++t)
            #pragma unroll
            for (int nt = 0; nt < 8; ++nt)
                #pragma unroll
                for (int r = 0; r < 4; ++r) {
                    float v = fmaf(A1[t][r], acc[t][nt][r], B1[t][r] * hbv[nt]);
                    v = fmaxf(v, 0.0f);
                    acc[t][nt][r] = v;
                    q2[t][r] = fmaf(v, v, q2[t][r]);
                }
    } else {
        #pragma unroll
        for (int t = 0; t < 2; ++t)
            #pragma unroll
            for (int nt = 0; nt < 8; ++nt)
                #pragma unroll
                for (int r = 0; r < 4; ++r) {
                    float v = fmaxf(A1[t][r] * acc[t][nt][r], 0.0f);
                    acc[t][nt][r] = v;
                    q2[t][r] = fmaf(v, v, q2[t][r]);
                }
    }
    #pragma unroll
    for (int m = 1; m <= 8; m <<= 1)
        #pragma unroll
        for (int t = 0; t < 2; ++t)
            #pragma unroll
            for (int r = 0; r < 4; ++r) q2[t][r] += __shfl_xor(q2[t][r], m);

    // ---- final scale: logmap0-scale * proj-scale folded into expmap0 + proj ----
    float K[2][4];
    #pragma unroll
    for (int t = 0; t < 2; ++t)
        #pragma unroll
        for (int r = 0; r < 4; ++r) {
            float sg = SG[t][r];
            float tn_t = sg * sqrtf(q2[t][r]);      // ||relu(logmap0(res3))||
            float tn = fmaxf(tn_t, MINNORM);
            float t4 = tanh_pos(tn);
            K[t][r] = fminf(t4, MAXNORM) * frcp(tn) * sg;
        }

    // ---- store: out_j = K * relu_val, fp32, direct from C layout ----
    #pragma unroll
    for (int t = 0; t < 2; ++t)
        #pragma unroll
        for (int r = 0; r < 4; ++r) {
            long row = rowbase + t * 16 + q * 4 + r;
            float* orow = Out + row * 128;
            #pragma unroll
            for (int nt = 0; nt < 8; ++nt)
                orow[nt * 16 + c] = K[t][r] * acc[t][nt][r];
        }
}

extern "C" void kernel_launch(void* const* d_in, const int* in_sizes, int n_in,
                              void* d_out, int out_size, void* d_ws, size_t ws_size,
                              hipStream_t stream) {
    const float* X = (const float*)d_in[0];   // fp32 [N,128]
    const float* W = (const float*)d_in[1];   // fp32 [128,128]
    const float* B = (const float*)d_in[2];   // fp32 [128]
    float* Out = (float*)d_out;
    short8* Wp = (short8*)d_ws;               // 32 KB packed bf16 W
    const int N = in_sizes[0] / 128;          // 524288 rows
    wpack_kernel<<<8, 256, 0, stream>>>(W, Wp);
    blinear_kernel<<<N / 128, 256, 0, stream>>>(X, Wp, B, Out);  // 128 rows/block
}

// Round 4
// 449.850 us; speedup vs baseline: 1.2071x; 1.0001x over previous
//
#include <hip/hip_runtime.h>

typedef __attribute__((ext_vector_type(8))) short short8;
typedef __attribute__((ext_vector_type(4))) float f32x4;
typedef __attribute__((ext_vector_type(4))) unsigned int u32x4;

#define MAXNORM 0.996f        // (1 - 4e-3)/sqrt(c), c=1
#define MINNORM 1e-15f
#define ATEPS   (1.0f - 1e-7f)

__device__ __forceinline__ float frcp(float x) { return __builtin_amdgcn_rcpf(x); }
// artanh on [0, 1-1e-7] with the reference clamp folded in
__device__ __forceinline__ float artanh_c(float z) {
    z = fminf(z, ATEPS);
    return 0.5f * __logf((1.0f + z) * frcp(1.0f - z));
}
// tanh for a >= 0
__device__ __forceinline__ float tanh_pos(float a) {
    float e = __expf(-2.0f * a);
    return (1.0f - e) * frcp(1.0f + e);
}
// fp32 -> bf16 bits, round-to-nearest-even (prologue only; hot path uses cvt_pk)
__device__ __forceinline__ unsigned short f2bf(float f) {
    union { float f; unsigned u; } v; v.f = f;
    unsigned r = v.u + 0x7FFFu + ((v.u >> 16) & 1u);
    return (unsigned short)(r >> 16);
}
// packed fp32x2 -> bf16x2, RNE (same rounding as f2bf), 1 instruction
__device__ __forceinline__ unsigned cvt_pk_bf16(float lo, float hi) {
    unsigned r;
    asm("v_cvt_pk_bf16_f32 %0, %1, %2" : "=v"(r) : "v"(lo), "v"(hi));
    return r;
}

// ---- prologue: pack W (fp32 [128,128]) into bf16 MFMA fragments ----
// Wp[(mt*4+ks)*64 + lane] = short8 { f2bf(W[mt*16+c][ks*32+q*8 + j]) }
// (unchanged layout; now consumed as the MFMA *A* operand -> transposed D)
__global__ __launch_bounds__(256) void wpack_kernel(
    const float* __restrict__ Wf, short8* __restrict__ Wp)
{
    const int tid = blockIdx.x * 256 + threadIdx.x;   // 0..2047
    const int l = tid & 63;
    const int f = tid >> 6;        // fragment id 0..31
    const int nt = f >> 2, ks = f & 3;
    const int c = l & 15, q = l >> 4;
    const float* src = Wf + (nt * 16 + c) * 128 + ks * 32 + q * 8;
    short8 s;
    #pragma unroll
    for (int j = 0; j < 4; ++j) {
        s[j]     = (short)f2bf(src[j]);
        s[4 + j] = (short)f2bf(src[4 + j]);
    }
    Wp[tid] = s;
}

// NOTE: plain __launch_bounds__(256). ",4" caps arch-VGPRs at 64 -> acc spills
// (measured R2: +410 MB scratch writes, dur 167->258 us). Do not re-add.
//
// TRANSPOSED GEMM: acc = mfma(Wfrag, Xfrag) => D = (X W^T)^T. Each lane owns
// full data rows (row = rowbase + t*16 + c); all row-reductions are in-lane
// + 2 shuffles, scalar chain 2x/lane (was 8x), stores are dwordx4.
__global__ __launch_bounds__(256) void blinear_kernel(
    const float* __restrict__ Xf,   // [N,128] fp32
    const short8* __restrict__ Wp,  // [32][64] packed bf16 fragments (32 KB)
    const float* __restrict__ Bf,   // [128] fp32
    float* __restrict__ Out)        // [N,128] fp32
{
    const int lane = threadIdx.x & 63;
    const int wave = threadIdx.x >> 6;
    const int c = lane & 15;   // data-row selector within 16-row tile
    const int q = lane >> 4;   // k-group on input side; out-col group on C side
    const long rowbase = (long)blockIdx.x * 128 + wave * 32;   // 32 rows per wave

    // ---- bias prologue: only hb2 needed on the hot path (b==0 => branches skip) ----
    float b0 = Bf[lane];
    float b1 = Bf[64 + lane];
    float bn2 = b0 * b0 + b1 * b1;
    #pragma unroll
    for (int m = 1; m <= 32; m <<= 1) bn2 += __shfl_xor(bn2, m);
    float bn = fmaxf(sqrtf(bn2), MINNORM);
    float fb = fminf(tanh_pos(bn), MAXNORM) * frcp(bn);   // hb = fb * b
    float hb2 = fb * fb * bn2;                            // sum(hb^2); wave-uniform

    // ---- X fragments: read once (fp32), pack to bf16 via cvt_pk; Sum(x^2) fp32 ----
    short8 afr[2][4];
    float xq[2] = {0.0f, 0.0f};
    #pragma unroll
    for (int t = 0; t < 2; ++t) {
        const float* xrow = Xf + (rowbase + t * 16 + c) * 128;
        #pragma unroll
        for (int ks = 0; ks < 4; ++ks) {
            f32x4 a0 = *(const f32x4*)(xrow + ks * 32 + q * 8);
            f32x4 a1 = *(const f32x4*)(xrow + ks * 32 + q * 8 + 4);
            #pragma unroll
            for (int j = 0; j < 4; ++j)
                xq[t] = fmaf(a0[j], a0[j], fmaf(a1[j], a1[j], xq[t]));
            union { u32x4 u; short8 s; } cv;
            cv.u[0] = cvt_pk_bf16(a0[0], a0[1]);
            cv.u[1] = cvt_pk_bf16(a0[2], a0[3]);
            cv.u[2] = cvt_pk_bf16(a1[0], a1[1]);
            cv.u[3] = cvt_pk_bf16(a1[2], a1[3]);
            afr[t][ks] = cv.s;
        }
    }
    // reduce Sum(x^2) across the 4 k-quads; result lands in the OWNING lane
    #pragma unroll
    for (int t = 0; t < 2; ++t) { xq[t] += __shfl_xor(xq[t], 16); xq[t] += __shfl_xor(xq[t], 32); }
    // xq[t] = ||x||^2 of this lane's row (rowbase + t*16 + c)

    // ---- GEMM, operands swapped: acc[t][mt][r] = mx[row t][col mt*16 + q*4 + r] ----
    f32x4 acc[2][8];
    {
        f32x4 z = {0.0f, 0.0f, 0.0f, 0.0f};
        #pragma unroll
        for (int t = 0; t < 2; ++t)
            #pragma unroll
            for (int mt = 0; mt < 8; ++mt) acc[t][mt] = z;
    }
    #pragma unroll
    for (int mt = 0; mt < 8; ++mt) {
        #pragma unroll
        for (int ks = 0; ks < 4; ++ks) {
            short8 bfr = Wp[(mt * 4 + ks) * 64 + lane];
            acc[0][mt] = __builtin_amdgcn_mfma_f32_16x16x32_bf16(bfr, afr[0][ks], acc[0][mt], 0, 0, 0);
            acc[1][mt] = __builtin_amdgcn_mfma_f32_16x16x32_bf16(bfr, afr[1][ks], acc[1][mt], 0, 0, 0);
        }
    }

    // ---- round-1 reductions: in-lane over 32 cols + xor16/xor32 across q-groups ----
    float mn2[2], mhb[2] = {0.0f, 0.0f};
    #pragma unroll
    for (int t = 0; t < 2; ++t) {
        float s0 = 0.0f, s1 = 0.0f;
        #pragma unroll
        for (int mt = 0; mt < 8; ++mt) {
            s0 = fmaf(acc[t][mt][0], acc[t][mt][0], fmaf(acc[t][mt][1], acc[t][mt][1], s0));
            s1 = fmaf(acc[t][mt][2], acc[t][mt][2], fmaf(acc[t][mt][3], acc[t][mt][3], s1));
        }
        mn2[t] = s0 + s1;
    }
    #pragma unroll
    for (int t = 0; t < 2; ++t) { mn2[t] += __shfl_xor(mn2[t], 16); mn2[t] += __shfl_xor(mn2[t], 32); }
    if (hb2 != 0.0f) {   // wave-uniform cold branch (b == 0 in this problem)
        #pragma unroll
        for (int mt = 0; mt < 8; ++mt) {
            f32x4 bb = *(const f32x4*)(Bf + mt * 16 + q * 4);
            #pragma unroll
            for (int t = 0; t < 2; ++t)
                #pragma unroll
                for (int r = 0; r < 4; ++r)
                    mhb[t] = fmaf(acc[t][mt][r], fb * bb[r], mhb[t]);
        }
        #pragma unroll
        for (int t = 0; t < 2; ++t) { mhb[t] += __shfl_xor(mhb[t], 16); mhb[t] += __shfl_xor(mhb[t], 32); }
    }

    // ---- per-row scalar chain: ONE row per lane per t (was 8 rows/lane) ----
    float A1[2], B1[2], SG[2];
    #pragma unroll
    for (int t = 0; t < 2; ++t) {
        float xn = fmaxf(sqrtf(xq[t]), MINNORM);
        float mn = fmaxf(sqrtf(mn2[t]), MINNORM);
        // mobius_matvec: res = tanh(mx_n/x_n * artanh(x_n)) * mx / mx_n, then proj
        float t1 = tanh_pos(mn * frcp(xn) * artanh_c(xn));
        float rn = fminf(t1, MAXNORM);          // ||res|| after proj
        float f1 = rn * frcp(mn);               // res = f1 * mx
        float x2 = rn * rn;
        // mobius_add(res, hb): res2 = (A*res + B*hb)/D
        float xy = f1 * mhb[t];
        float Aa = 1.0f + 2.0f * xy + hb2;
        float Bb = 1.0f - x2;
        float Dn = fmaxf(1.0f + 2.0f * xy + x2 * hb2, MINNORM);
        float rD = frcp(Dn);
        float a1 = Aa * f1 * rD;                // res2 = a1*mx + b1_*hb
        float b1_ = Bb * rD;
        float r2n2 = a1 * a1 * mn2[t] + 2.0f * a1 * b1_ * mhb[t] + b1_ * b1_ * hb2;
        float r2n = sqrtf(fmaxf(r2n2, 0.0f));
        float g = (r2n > MAXNORM) ? (MAXNORM * frcp(r2n)) : 1.0f;   // proj
        float n3 = fmaxf(fminf(r2n, MAXNORM), MINNORM);
        float s3 = artanh_c(n3) * frcp(n3);     // logmap0 scale (>0, commutes with relu)
        A1[t] = a1; B1[t] = b1_; SG[t] = s3 * g;
    }

    // ---- round-2: relu + q2 (in-lane + 2 shuffles). Hot path folds A1 out. ----
    float q2[2] = {0.0f, 0.0f};
    float sA[2];
    if (hb2 != 0.0f) {
        #pragma unroll
        for (int mt = 0; mt < 8; ++mt) {
            f32x4 bb = *(const f32x4*)(Bf + mt * 16 + q * 4);
            #pragma unroll
            for (int t = 0; t < 2; ++t)
                #pragma unroll
                for (int r = 0; r < 4; ++r) {
                    float v = fmaf(A1[t], acc[t][mt][r], B1[t] * (fb * bb[r]));
                    v = fmaxf(v, 0.0f);
                    acc[t][mt][r] = v;
                    q2[t] = fmaf(v, v, q2[t]);
                }
        }
        sA[0] = 1.0f; sA[1] = 1.0f;
    } else {
        #pragma unroll
        for (int t = 0; t < 2; ++t) {
            float s0 = 0.0f, s1 = 0.0f;
            #pragma unroll
            for (int mt = 0; mt < 8; ++mt) {
                #pragma unroll
                for (int r = 0; r < 4; ++r) acc[t][mt][r] = fmaxf(acc[t][mt][r], 0.0f);
                s0 = fmaf(acc[t][mt][0], acc[t][mt][0], fmaf(acc[t][mt][1], acc[t][mt][1], s0));
                s1 = fmaf(acc[t][mt][2], acc[t][mt][2], fmaf(acc[t][mt][3], acc[t][mt][3], s1));
            }
            q2[t] = s0 + s1;
            sA[t] = A1[t];   // v = A1 * relu(acc), A1 > 0; fold into final scale
        }
    }
    #pragma unroll
    for (int t = 0; t < 2; ++t) { q2[t] += __shfl_xor(q2[t], 16); q2[t] += __shfl_xor(q2[t], 32); }

    // ---- final scale: logmap0 * proj folded into expmap0 + proj ----
    float OS[2];
    #pragma unroll
    for (int t = 0; t < 2; ++t) {
        float sgs = SG[t] * sA[t];
        float tn_t = sgs * sqrtf(q2[t]);        // ||relu(logmap0(res3))||
        float tn = fmaxf(tn_t, MINNORM);
        float t4 = tanh_pos(tn);
        OS[t] = fminf(t4, MAXNORM) * frcp(tn) * sgs;
    }

    // ---- store: dwordx4, 16 rows x 64 B contiguous per instruction ----
    #pragma unroll
    for (int t = 0; t < 2; ++t) {
        float* orow = Out + (rowbase + t * 16 + c) * 128 + q * 4;
        #pragma unroll
        for (int mt = 0; mt < 8; ++mt) {
            f32x4 o;
            #pragma unroll
            for (int r = 0; r < 4; ++r) o[r] = OS[t] * acc[t][mt][r];
            *(f32x4*)(orow + mt * 16) = o;
        }
    }
}

extern "C" void kernel_launch(void* const* d_in, const int* in_sizes, int n_in,
                              void* d_out, int out_size, void* d_ws, size_t ws_size,
                              hipStream_t stream) {
    const float* X = (const float*)d_in[0];   // fp32 [N,128]
    const float* W = (const float*)d_in[1];   // fp32 [128,128]
    const float* B = (const float*)d_in[2];   // fp32 [128]
    float* Out = (float*)d_out;
    short8* Wp = (short8*)d_ws;               // 32 KB packed bf16 W
    const int N = in_sizes[0] / 128;          // 524288 rows
    wpack_kernel<<<8, 256, 0, stream>>>(W, Wp);
    blinear_kernel<<<N / 128, 256, 0, stream>>>(X, Wp, B, Out);  // 128 rows/block
}